// Round 4
// baseline (207.732 us; speedup 1.0000x reference)
//
#include <hip/hip_runtime.h>
#include <math.h>

namespace {

constexpr int Bc   = 16;    // batch
constexpr int Hc   = 16;    // heads
constexpr int Dc   = 128;   // head dim (K/Q)
constexpr int LVc  = 128;   // head dim (V)
constexpr int SPLc = 4;     // kv splits
constexpr float LOGIT_CAP = 30.0f;
constexpr float SM_SCALE  = 0.08838834764831845f;   // 1/sqrt(128)

// ---------------------------------------------------------------------------
// Kernel A: one block per (b, h, s, half). 2048 blocks x 256 threads,
// __launch_bounds__(256,8) -> 8 blocks/CU = 32 waves/CU (max occupancy) for
// latency hiding. Same proven R1 loop: 8 groups x 32 lanes, each group
// streams tokens, lanes cover the 128-dim row as float4 (coalesced 512 B).
// Fixed softmax shift m=30 (tanh caps logits at 30) -> partials merge by
// pure addition. p = exp(30*tanh(z/30)-30) = exp(-60/(e^{z/15}+1)).
// ---------------------------------------------------------------------------
__launch_bounds__(256, 8)
__global__ void attn_half(const float* __restrict__ q,
                          const float* __restrict__ kbuf,
                          const float* __restrict__ vbuf,
                          const int*   __restrict__ indptr,
                          const int*   __restrict__ indices,
                          const int*   __restrict__ nsplits,
                          float*       __restrict__ accW,
                          float*       __restrict__ esumW)
{
    const int bid  = blockIdx.x;            // ((b*H + h)*S + s)*2 + half
    const int half = bid & 1;
    const int s    = (bid >> 1) & (SPLc - 1);
    const int h    = (bid >> 3) & (Hc - 1);
    const int b    = bid >> 7;

    const int tid  = threadIdx.x;
    const int g    = tid >> 5;              // group 0..7
    const int lane = tid & 31;

    const int kv_start = indptr[b];
    const int kv_len   = indptr[b + 1] - kv_start;
    const int ns       = nsplits[b];
    const int Ls       = kv_len / ns;       // 1024
    const int h0       = Ls >> 1;
    const int lo       = half * h0;
    const int cnt      = half ? (Ls - h0) : h0;   // 512
    const int tok0     = kv_start + s * Ls + lo;

    __shared__ int   s_idx[512];
    __shared__ float s_merge[8 * 128];
    __shared__ float s_esum[8];

    for (int i = tid; i < cnt; i += 256) s_idx[i] = indices[tok0 + i];

    const float4 q4 = *reinterpret_cast<const float4*>(
        q + ((size_t)b * Hc + h) * Dc + 4 * lane);
    __syncthreads();

    float4 acc = make_float4(0.f, 0.f, 0.f, 0.f);
    float  esum = 0.f;

    #pragma unroll 4
    for (int l = g; l < cnt; l += 8) {
        const int idx = s_idx[l];
        const size_t row = ((size_t)idx * Hc + h);
        const float4 k4 = *reinterpret_cast<const float4*>(kbuf + row * Dc  + 4 * lane);
        const float4 v4 = *reinterpret_cast<const float4*>(vbuf + row * LVc + 4 * lane);

        float part = q4.x * k4.x + q4.y * k4.y + q4.z * k4.z + q4.w * k4.w;
        part += __shfl_xor(part, 16);       // xor<=16 stays inside the 32-lane group
        part += __shfl_xor(part, 8);
        part += __shfl_xor(part, 4);
        part += __shfl_xor(part, 2);
        part += __shfl_xor(part, 1);

        const float e = __expf(part * (SM_SCALE / 15.0f));
        const float p = __expf(-60.0f / (e + 1.0f));   // = exp(30*tanh(z/30) - 30)
        esum += p;
        acc.x += p * v4.x; acc.y += p * v4.y; acc.z += p * v4.z; acc.w += p * v4.w;
    }

    // 8-way group merge
    *reinterpret_cast<float4*>(&s_merge[g * 128 + 4 * lane]) = acc;
    if (lane == 0) s_esum[g] = esum;
    __syncthreads();
    #pragma unroll
    for (int off = 4; off >= 1; off >>= 1) {
        if (g < off) {
            float4 a = *reinterpret_cast<float4*>(&s_merge[g * 128 + 4 * lane]);
            const float4 c = *reinterpret_cast<const float4*>(&s_merge[(g + off) * 128 + 4 * lane]);
            a.x += c.x; a.y += c.y; a.z += c.z; a.w += c.w;
            *reinterpret_cast<float4*>(&s_merge[g * 128 + 4 * lane]) = a;
            if (lane == 0) s_esum[g] += s_esum[g + off];
        }
        __syncthreads();
    }

    if (g == 0) {
        const float4 r = *reinterpret_cast<const float4*>(&s_merge[4 * lane]);
        *reinterpret_cast<float4*>(accW + (size_t)bid * 128 + 4 * lane) = r;
        if (lane == 0) esumW[bid] = s_esum[0];
    }
}

// ---------------------------------------------------------------------------
// Kernel B: merge the two halves; 1024 blocks x 128 threads.
// ---------------------------------------------------------------------------
__global__ void attn_merge(const float* __restrict__ accW,
                           const float* __restrict__ esumW,
                           float*       __restrict__ out)
{
    const int bid = blockIdx.x;             // (b*H + h)*S + s
    const int d   = threadIdx.x;            // 0..127
    const float a  = accW[(size_t)(2 * bid) * 128 + d]
                   + accW[(size_t)(2 * bid + 1) * 128 + d];
    const float es = esumW[2 * bid] + esumW[2 * bid + 1];
    out[(size_t)bid * LVc + d] = a / es;
    if (d == 0)
        out[(size_t)Bc * Hc * SPLc * LVc + bid] = LOGIT_CAP + logf(es);
}

// ---------------------------------------------------------------------------
// Fallback (R1 single-kernel) if ws_size is too small.
// ---------------------------------------------------------------------------
__launch_bounds__(256, 4)
__global__ void decode_attn_fb(const float* __restrict__ q,
                               const float* __restrict__ kbuf,
                               const float* __restrict__ vbuf,
                               const int*   __restrict__ indptr,
                               const int*   __restrict__ indices,
                               const int*   __restrict__ nsplits,
                               float*       __restrict__ out)
{
    const int bid = blockIdx.x;
    const int s   = bid & (SPLc - 1);
    const int h   = (bid >> 2) & (Hc - 1);
    const int b   = bid >> 6;
    const int tid  = threadIdx.x;
    const int g    = tid >> 5;
    const int lane = tid & 31;

    const int kv_start = indptr[b];
    const int kv_len   = indptr[b + 1] - kv_start;
    const int ns       = nsplits[b];
    const int Ls       = kv_len / ns;
    const int tok0     = kv_start + s * Ls;

    __shared__ int   s_idx[1024];
    __shared__ float s_merge[8 * 128];
    __shared__ float s_esum[8];

    for (int i = tid; i < Ls; i += 256) s_idx[i] = indices[tok0 + i];
    const float4 q4 = *reinterpret_cast<const float4*>(
        q + ((size_t)b * Hc + h) * Dc + 4 * lane);
    __syncthreads();

    float4 acc = make_float4(0.f, 0.f, 0.f, 0.f);
    float  esum = 0.f;

    #pragma unroll 4
    for (int l = g; l < Ls; l += 8) {
        const int idx = s_idx[l];
        const size_t row = ((size_t)idx * Hc + h);
        const float4 k4 = *reinterpret_cast<const float4*>(kbuf + row * Dc  + 4 * lane);
        const float4 v4 = *reinterpret_cast<const float4*>(vbuf + row * LVc + 4 * lane);
        float part = q4.x * k4.x + q4.y * k4.y + q4.z * k4.z + q4.w * k4.w;
        part += __shfl_xor(part, 16);
        part += __shfl_xor(part, 8);
        part += __shfl_xor(part, 4);
        part += __shfl_xor(part, 2);
        part += __shfl_xor(part, 1);
        const float e = __expf(part * (SM_SCALE / 15.0f));
        const float p = __expf(-60.0f / (e + 1.0f));
        esum += p;
        acc.x += p * v4.x; acc.y += p * v4.y; acc.z += p * v4.z; acc.w += p * v4.w;
    }

    *reinterpret_cast<float4*>(&s_merge[g * 128 + 4 * lane]) = acc;
    if (lane == 0) s_esum[g] = esum;
    __syncthreads();
    #pragma unroll
    for (int off = 4; off >= 1; off >>= 1) {
        if (g < off) {
            float4 a = *reinterpret_cast<float4*>(&s_merge[g * 128 + 4 * lane]);
            const float4 cc = *reinterpret_cast<const float4*>(&s_merge[(g + off) * 128 + 4 * lane]);
            a.x += cc.x; a.y += cc.y; a.z += cc.z; a.w += cc.w;
            *reinterpret_cast<float4*>(&s_merge[g * 128 + 4 * lane]) = a;
            if (lane == 0) s_esum[g] += s_esum[g + off];
        }
        __syncthreads();
    }
    if (g == 0) {
        const float es  = s_esum[0];
        const float inv = 1.0f / es;
        float4 r = *reinterpret_cast<const float4*>(&s_merge[4 * lane]);
        r.x *= inv; r.y *= inv; r.z *= inv; r.w *= inv;
        float* outp = out + (((size_t)b * Hc + h) * SPLc + s) * LVc + 4 * lane;
        *reinterpret_cast<float4*>(outp) = r;
        if (lane == 0)
            out[(size_t)Bc * Hc * SPLc * LVc + ((size_t)b * Hc + h) * SPLc + s] =
                LOGIT_CAP + logf(es);
    }
}

} // anonymous namespace

extern "C" void kernel_launch(void* const* d_in, const int* in_sizes, int n_in,
                              void* d_out, int out_size, void* d_ws, size_t ws_size,
                              hipStream_t stream) {
    const float* q       = (const float*)d_in[0];
    const float* kbuf    = (const float*)d_in[1];
    const float* vbuf    = (const float*)d_in[2];
    const int*   indptr  = (const int*)d_in[3];
    const int*   indices = (const int*)d_in[4];
    const int*   nspl    = (const int*)d_in[5];
    float* outp = (float*)d_out;

    const int   nHalf     = Bc * Hc * SPLc * 2;                 // 2048
    const size_t accFloats = (size_t)nHalf * 128;               // 262144
    const size_t needed    = (accFloats + nHalf) * sizeof(float);  // ~1.06 MB

    if (ws_size >= needed) {
        float* accW  = (float*)d_ws;
        float* esumW = accW + accFloats;
        hipLaunchKernelGGL(attn_half, dim3(nHalf), dim3(256), 0, stream,
                           q, kbuf, vbuf, indptr, indices, nspl, accW, esumW);
        hipLaunchKernelGGL(attn_merge, dim3(Bc * Hc * SPLc), dim3(128), 0, stream,
                           accW, esumW, outp);
    } else {
        hipLaunchKernelGGL(decode_attn_fb, dim3(Bc * Hc * SPLc), dim3(256), 0, stream,
                           q, kbuf, vbuf, indptr, indices, nspl, outp);
    }
}

// Round 6
// 165.917 us; speedup vs baseline: 1.2520x; 1.2520x over previous
//
#include <hip/hip_runtime.h>
#include <math.h>

namespace {

constexpr int Bc   = 16;    // batch
constexpr int Hc   = 16;    // heads
constexpr int Dc   = 128;   // head dim (K/Q)
constexpr int LVc  = 128;   // head dim (V)
constexpr int SPLc = 4;     // kv splits
constexpr float LOGIT_CAP = 30.0f;
constexpr float SM_SCALE  = 0.08838834764831845f;   // 1/sqrt(128)

typedef float floatx4 __attribute__((ext_vector_type(4)));  // native vec for nontemporal builtin

// One block per (b, h, s). 256 threads = 8 groups x 32 lanes (R1 structure,
// best so far: 189.5 us). Single streaming pass with fixed softmax shift
// m=30 (tanh caps logits at 30): p = exp(30*tanh(z/30)-30) = exp(-60/(e^{z/15}+1)).
// This round: unroll 8 (8 KB in flight per wave, fits 128-VGPR budget at
// 4 blocks/CU) + non-temporal K/V loads (pure streaming, zero reuse).
__launch_bounds__(256, 4)
__global__ void decode_attn(const float* __restrict__ q,
                            const float* __restrict__ kbuf,
                            const float* __restrict__ vbuf,
                            const int*   __restrict__ indptr,
                            const int*   __restrict__ indices,
                            const int*   __restrict__ nsplits,
                            float*       __restrict__ out)
{
    const int bid = blockIdx.x;             // b*H*S + h*S + s
    const int s   = bid & (SPLc - 1);
    const int h   = (bid >> 2) & (Hc - 1);
    const int b   = bid >> 6;

    const int tid  = threadIdx.x;
    const int g    = tid >> 5;              // group 0..7
    const int lane = tid & 31;              // lane within group

    const int kv_start = indptr[b];
    const int kv_len   = indptr[b + 1] - kv_start;
    const int ns       = nsplits[b];
    const int Ls       = kv_len / ns;       // tokens in this split (1024)
    const int tok0     = kv_start + s * Ls;

    __shared__ int   s_idx[1024];
    __shared__ float s_merge[8 * 128];
    __shared__ float s_esum[8];

    // stage gathered indices (coalesced)
    for (int i = tid; i < Ls; i += 256)
        s_idx[i] = indices[tok0 + i];

    // q fragment in registers (loop-invariant)
    const floatx4 q4 = *reinterpret_cast<const floatx4*>(
        q + ((size_t)b * Hc + h) * Dc + 4 * lane);

    __syncthreads();

    floatx4 acc = (floatx4)(0.f);
    float   esum = 0.f;                     // uniform across the 32-lane group

    #pragma unroll 8
    for (int l = g; l < Ls; l += 8) {
        const int idx = s_idx[l];
        const size_t row = ((size_t)idx * Hc + h);
        const floatx4 k4 = __builtin_nontemporal_load(
            reinterpret_cast<const floatx4*>(kbuf + row * Dc  + 4 * lane));
        const floatx4 v4 = __builtin_nontemporal_load(
            reinterpret_cast<const floatx4*>(vbuf + row * LVc + 4 * lane));

        float part = q4.x * k4.x + q4.y * k4.y + q4.z * k4.z + q4.w * k4.w;
        part += __shfl_xor(part, 16);       // xor<=16 stays inside the 32-lane group
        part += __shfl_xor(part, 8);
        part += __shfl_xor(part, 4);
        part += __shfl_xor(part, 2);
        part += __shfl_xor(part, 1);

        const float e = __expf(part * (SM_SCALE / 15.0f));
        const float p = __expf(-60.0f / (e + 1.0f));   // = exp(30*tanh(z/30) - 30)
        esum += p;
        acc += p * v4;
    }

    // ---------------- 8-way group merge ----------------
    *reinterpret_cast<floatx4*>(&s_merge[g * 128 + 4 * lane]) = acc;
    if (lane == 0) s_esum[g] = esum;
    __syncthreads();

    #pragma unroll
    for (int off = 4; off >= 1; off >>= 1) {
        if (g < off) {
            floatx4 a = *reinterpret_cast<floatx4*>(&s_merge[g * 128 + 4 * lane]);
            const floatx4 c = *reinterpret_cast<const floatx4*>(&s_merge[(g + off) * 128 + 4 * lane]);
            a += c;
            *reinterpret_cast<floatx4*>(&s_merge[g * 128 + 4 * lane]) = a;
            if (lane == 0) s_esum[g] += s_esum[g + off];
        }
        __syncthreads();
    }

    // ---------------- epilogue ----------------
    if (g == 0) {
        const float es  = s_esum[0];
        const float inv = 1.0f / es;
        floatx4 r = *reinterpret_cast<const floatx4*>(&s_merge[4 * lane]);
        r *= inv;
        float* outp = out + (((size_t)b * Hc + h) * SPLc + s) * LVc + 4 * lane;
        *reinterpret_cast<floatx4*>(outp) = r;
        if (lane == 0) {
            out[(size_t)Bc * Hc * SPLc * LVc + ((size_t)b * Hc + h) * SPLc + s] =
                LOGIT_CAP + logf(es);
        }
    }
}

} // anonymous namespace

extern "C" void kernel_launch(void* const* d_in, const int* in_sizes, int n_in,
                              void* d_out, int out_size, void* d_ws, size_t ws_size,
                              hipStream_t stream) {
    const float* q       = (const float*)d_in[0];
    const float* kbuf    = (const float*)d_in[1];
    const float* vbuf    = (const float*)d_in[2];
    const int*   indptr  = (const int*)d_in[3];
    const int*   indices = (const int*)d_in[4];
    const int*   nspl    = (const int*)d_in[5];
    float* outp = (float*)d_out;

    dim3 grid(Bc * Hc * SPLc);   // 1024 blocks: one per (b, h, split)
    dim3 block(256);
    hipLaunchKernelGGL(decode_attn, grid, block, 0, stream,
                       q, kbuf, vbuf, indptr, indices, nspl, outp);
}